// Round 5
// baseline (99.877 us; speedup 1.0000x reference)
//
#include <hip/hip_runtime.h>
#include <math.h>

#define CIN    384
#define NPIX   3136      // 56*56
#define OCH    1920
#define P_PAD  896

typedef float vf4 __attribute__((ext_vector_type(4)));
typedef __attribute__((ext_vector_type(4))) float f32x4;
typedef __attribute__((ext_vector_type(8))) short bf16x8;
typedef __attribute__((ext_vector_type(8))) unsigned short u16x8;

__device__ __forceinline__ unsigned short f2bf(float f) {
    unsigned u = __float_as_uint(f);
    u = (u + 0x7FFF + ((u >> 16) & 1)) >> 16;
    return (unsigned short)u;
}
__device__ __forceinline__ float bf2f(unsigned short h) {
    return __uint_as_float(((unsigned)h) << 16);
}

// ---------------------------------------------------------------------------
// k_prep: split proj_w [1920][384] fp32 -> Whi/Wlo bf16 (row-major, k-contig)
// ---------------------------------------------------------------------------
__global__ __launch_bounds__(256) void k_prep(const float* __restrict__ W,
                                              unsigned short* __restrict__ Whi,
                                              unsigned short* __restrict__ Wlo) {
    int i = blockIdx.x * 256 + threadIdx.x;   // 737280 = 2880*256 exact
    float w = W[i];
    unsigned short hi = f2bf(w);
    Whi[i] = hi;
    Wlo[i] = f2bf(w - bf2f(hi));
}

// ---------------------------------------------------------------------------
// Kernel 1: pool x (16,384,56,56) -> Xhi/Xlo bf16 TRANSPOSED [p=896][k=384]
//   p in [0,784): Bi*49 + n (7x7 agent, mean 8x8); [784,848): clusters; pad 0
// ---------------------------------------------------------------------------
__global__ __launch_bounds__(256) void k_pool(const float* __restrict__ x,
                                              unsigned short* __restrict__ Xhi,
                                              unsigned short* __restrict__ Xlo) {
    int blk = blockIdx.x;          // 16*384
    int Bi = blk / CIN;
    int ch = blk - Bi * CIN;
    __shared__ float ps[56][14];
    __shared__ float s14[14][14];
    const float* xp = x + (size_t)(Bi * CIN + ch) * NPIX;
    int t = threadIdx.x;
    for (int p = t; p < 784; p += 256) {
        int row = p / 14, cb = p % 14;
        const vf4 v = __builtin_nontemporal_load(
            reinterpret_cast<const vf4*>(xp + row * 56 + cb * 4));
        ps[row][cb] = v.x + v.y + v.z + v.w;
    }
    __syncthreads();
    if (t < 196) {
        int ri = t / 14, cb = t % 14;
        s14[ri][cb] = ps[4*ri][cb] + ps[4*ri+1][cb] + ps[4*ri+2][cb] + ps[4*ri+3][cb];
    }
    __syncthreads();
    if (t < 49) {
        int i = t / 7, j = t % 7;
        float s = (s14[2*i][2*j] + s14[2*i][2*j+1] + s14[2*i+1][2*j] + s14[2*i+1][2*j+1])
                  * (1.0f / 64.0f);
        int p = Bi * 49 + t;
        unsigned short hi = f2bf(s);
        Xhi[(size_t)p * 384 + ch] = hi;
        Xlo[(size_t)p * 384 + ch] = f2bf(s - bf2f(hi));
    } else if (t >= 64 && t < 68) {
        int m = t - 64;
        int mi = m / 2, mj = m % 2;
        float s = 0.f;
        for (int ri = 7*mi; ri < 7*mi + 7; ++ri)
            for (int cb = 7*mj; cb < 7*mj + 7; ++cb)
                s += s14[ri][cb];
        s *= (1.0f / 784.0f);
        int p = 784 + Bi * 4 + m;
        unsigned short hi = f2bf(s);
        Xhi[(size_t)p * 384 + ch] = hi;
        Xlo[(size_t)p * 384 + ch] = f2bf(s - bf2f(hi));
    } else if (t >= 128 && t < 176 && Bi == 0) {
        int p = 848 + (t - 128);
        Xhi[(size_t)p * 384 + ch] = 0;
        Xlo[(size_t)p * 384 + ch] = 0;
    }
}

// ---------------------------------------------------------------------------
// Kernel 2: y_cat[1920][896] = W @ x + b via bf16x3 MFMA (fp32-accurate)
// block 64x64 (4 waves, each 32x32 = 2x2 frags of 16x16x32), K=384 in 12 steps
// ---------------------------------------------------------------------------
__global__ __launch_bounds__(256) void k_gemm1m(
        const unsigned short* __restrict__ Whi, const unsigned short* __restrict__ Wlo,
        const unsigned short* __restrict__ Xhi, const unsigned short* __restrict__ Xlo,
        const float* __restrict__ bias, float* __restrict__ y_cat) {
    int n0 = blockIdx.x * 64, m0 = blockIdx.y * 64;
    __shared__ unsigned short Ah[64][40], Al[64][40], Bh[64][40], Bl[64][40];
    int t = threadIdx.x;
    int lane = t & 63, wave = t >> 6;
    int wm = wave >> 1, wn = wave & 1;          // 2x2 wave grid
    int fr = lane & 15, fq = lane >> 4;         // frag row / k-quarter
    int srow = t >> 2, sck = (t & 3) * 8;       // staging: row, k-chunk
    f32x4 acc[2][2] = {};
    const size_t aoff = (size_t)(m0 + srow) * 384 + sck;
    const size_t boff = (size_t)(n0 + srow) * 384 + sck;
    for (int k0 = 0; k0 < 384; k0 += 32) {
        *(u16x8*)&Ah[srow][sck] = *(const u16x8*)(Whi + aoff + k0);
        *(u16x8*)&Al[srow][sck] = *(const u16x8*)(Wlo + aoff + k0);
        *(u16x8*)&Bh[srow][sck] = *(const u16x8*)(Xhi + boff + k0);
        *(u16x8*)&Bl[srow][sck] = *(const u16x8*)(Xlo + boff + k0);
        __syncthreads();
        bf16x8 ah[2], al[2], bh[2], bl[2];
#pragma unroll
        for (int mi = 0; mi < 2; ++mi) {
            int r = wm * 32 + mi * 16 + fr;
            ah[mi] = *(const bf16x8*)&Ah[r][fq * 8];
            al[mi] = *(const bf16x8*)&Al[r][fq * 8];
        }
#pragma unroll
        for (int ni = 0; ni < 2; ++ni) {
            int r = wn * 32 + ni * 16 + fr;
            bh[ni] = *(const bf16x8*)&Bh[r][fq * 8];
            bl[ni] = *(const bf16x8*)&Bl[r][fq * 8];
        }
#pragma unroll
        for (int mi = 0; mi < 2; ++mi)
#pragma unroll
            for (int ni = 0; ni < 2; ++ni) {
                acc[mi][ni] = __builtin_amdgcn_mfma_f32_16x16x32_bf16(ah[mi], bh[ni], acc[mi][ni], 0, 0, 0);
                acc[mi][ni] = __builtin_amdgcn_mfma_f32_16x16x32_bf16(ah[mi], bl[ni], acc[mi][ni], 0, 0, 0);
                acc[mi][ni] = __builtin_amdgcn_mfma_f32_16x16x32_bf16(al[mi], bh[ni], acc[mi][ni], 0, 0, 0);
            }
        __syncthreads();
    }
    // C/D layout: col = lane&15, row = (lane>>4)*4 + reg
#pragma unroll
    for (int mi = 0; mi < 2; ++mi)
#pragma unroll
        for (int j = 0; j < 4; ++j) {
            int m = m0 + wm * 32 + mi * 16 + fq * 4 + j;
            float bb = bias[m];
#pragma unroll
            for (int ni = 0; ni < 2; ++ni) {
                int p = n0 + wn * 32 + ni * 16 + fr;
                y_cat[(size_t)m * P_PAD + p] = acc[mi][ni][j] + bb;
            }
        }
}

// ---------------------------------------------------------------------------
// Kernel 3: per-(B,head) cluster attention -> osmall[16][384][49]
// ---------------------------------------------------------------------------
__global__ __launch_bounds__(512) void k_attn(const float* __restrict__ y_cat,
                                              const float* __restrict__ alpha,
                                              const float* __restrict__ beta,
                                              float* __restrict__ osmall) {
    int bb = blockIdx.x;           // 128
    int Bi = bb >> 3, head = bb & 7;
    __shared__ float kL[2][48][49];
    __shared__ float vL[2][49][48];
    __shared__ float pL[48][49];
    __shared__ float kcL[2][4][48], vcL[2][4][48];
    __shared__ float e0[4][49], memb[4][49];
    __shared__ float rowmax0[4], esum0[4], msum[4];
    __shared__ float agg[8][48];
    __shared__ float anorm[8], pnorm[49];
    __shared__ float assignW[8][49];
    int t = threadIdx.x;
    size_t colbase = (size_t)Bi * 49;

    for (int idx = t; idx < 5 * 2352; idx += 512) {
        int g = idx / 2352, rem = idx % 2352;
        int cc = rem / 49, n = rem % 49;
        float v = y_cat[(size_t)(g * 384 + head * 48 + cc) * P_PAD + colbase + n];
        if (g == 0)      pL[cc][n] = v;
        else if (g == 1) kL[0][cc][n] = v;
        else if (g == 2) vL[0][n][cc] = v;
        else if (g == 3) kL[1][cc][n] = v;
        else             vL[1][n][cc] = v;
    }
    for (int idx = t; idx < 768; idx += 512) {
        int i = idx / 384, rem = idx % 384;
        int kv = rem / 192, rem2 = rem % 192;
        int m = rem2 / 48, cc = rem2 % 48;
        float v = y_cat[(size_t)((1 + 2*i + kv) * 384 + head * 48 + cc) * P_PAD + 784 + Bi * 4 + m];
        if (kv == 0) kcL[i][m][cc] = v; else vcL[i][m][cc] = v;
    }
    __syncthreads();

    const float scale = 0.14433756729740643f;  // 1/sqrt(48)
    if (t < 392) {
        int i = t / 196, r = t % 196;
        int m = r / 49, n = r % 49;
        float s = 0.f;
        for (int cc = 0; cc < 48; ++cc) s += kcL[i][m][cc] * kL[i][cc][n];
        s *= scale;
        if (i == 0) e0[m][n] = s; else memb[m][n] = s;
    }
    __syncthreads();
    if (t < 4) {
        float mx = -1e30f;
        for (int n = 0; n < 49; ++n) mx = fmaxf(mx, e0[t][n]);
        rowmax0[t] = mx;
    }
    __syncthreads();
    if (t < 196) { int m = t / 49, n = t % 49; e0[m][n] = expf(e0[m][n] - rowmax0[m]); }
    __syncthreads();
    if (t < 4) { float s = 0.f; for (int n = 0; n < 49; ++n) s += e0[t][n]; esum0[t] = s; }
    if (t >= 64 && t < 113) {
        int n = t - 64;
        float a0 = memb[0][n], a1 = memb[1][n], a2 = memb[2][n], a3 = memb[3][n];
        float mx = fmaxf(fmaxf(a0, a1), fmaxf(a2, a3));
        float x0 = expf(a0 - mx), x1 = expf(a1 - mx), x2 = expf(a2 - mx), x3 = expf(a3 - mx);
        float s = x0 + x1 + x2 + x3;
        memb[0][n] = x0 / s; memb[1][n] = x1 / s; memb[2][n] = x2 / s; memb[3][n] = x3 / s;
    }
    __syncthreads();
    if (t < 4) { float s = 0.f; for (int n = 0; n < 49; ++n) s += memb[t][n]; msum[t] = s; }
    __syncthreads();
    if (t < 384) {
        int row = t / 48, cc = t % 48;
        float acc = 0.f;
        if (row < 4) {
            for (int n = 0; n < 49; ++n) acc += e0[row][n] * vL[0][n][cc];
            agg[row][cc] = acc / esum0[row] + vcL[0][row][cc];
        } else {
            int m = row - 4;
            for (int n = 0; n < 49; ++n) acc += memb[m][n] * vL[1][n][cc];
            agg[row][cc] = acc / (msum[m] + 1e-6f) + vcL[1][m][cc];
        }
    }
    __syncthreads();
    if (t < 8) {
        float s = 0.f;
        for (int cc = 0; cc < 48; ++cc) { float a = agg[t][cc]; s += a * a; }
        anorm[t] = sqrtf(s) + 1e-6f;
    }
    if (t >= 64 && t < 113) {
        int n = t - 64; float s = 0.f;
        for (int cc = 0; cc < 48; ++cc) { float a = pL[cc][n]; s += a * a; }
        pnorm[n] = sqrtf(s) + 1e-6f;
    }
    __syncthreads();
    if (t < 49) {
        int n = t;
        float sims[8];
        float mx = -1e30f;
        for (int m = 0; m < 8; ++m) {
            float dot = 0.f;
            for (int cc = 0; cc < 48; ++cc) dot += agg[m][cc] * pL[cc][n];
            float sv = alpha[m] * (dot / (anorm[m] * pnorm[n])) + beta[m];
            sims[m] = sv; mx = fmaxf(mx, sv);
        }
        float ssum = 0.f;
        for (int m = 0; m < 8; ++m) { float e = expf(sims[m] - mx); sims[m] = e; ssum += e; }
        for (int m = 0; m < 8; ++m) assignW[m][n] = sims[m] / ssum;
    }
    __syncthreads();
    for (int idx = t; idx < 2352; idx += 512) {
        int cc = idx / 49, n = idx % 49;
        float s = 0.f;
        for (int m = 0; m < 8; ++m) s += agg[m][cc] * assignW[m][n];
        osmall[((size_t)Bi * 384 + head * 48 + cc) * 49 + n] = s;
    }
}

// ---------------------------------------------------------------------------
// Kernel 4: fused proj2 GEMM (K chunked through LDS, reg accum) + bilinear up
// one block per (Bi, 16-ch tile): 384 blocks, 256 threads, ~48 KB LDS
// ---------------------------------------------------------------------------
__global__ __launch_bounds__(256) void k_out2(const float* __restrict__ osmall,
                                              const float* __restrict__ W2,
                                              const float* __restrict__ b2,
                                              float* __restrict__ out) {
    int blk = blockIdx.x;
    int Bi = blk / 24, ot = blk % 24;
    __shared__ float smem[6208 + 4992 + 832];  // Wt[16][388] | Os[96][52]/zbuf | zL[16][52]
    float* Wt = smem;
    float* Os = smem + 6208;
    float* zL = smem + 11200;
    int t = threadIdx.x;
    for (int idx = t; idx < 16 * 384; idx += 256) {
        int r = idx / 384, k = idx - r * 384;
        Wt[r * 388 + k] = W2[(size_t)(ot * 16 + r) * 384 + k];
    }
    int ks = 0, rgq = 0, nq = 0;
    if (t < 208) { ks = t / 52; int rem = t - ks * 52; rgq = rem / 13; nq = rem - rgq * 13; }
    float4 acc0 = {0,0,0,0}, acc1 = {0,0,0,0}, acc2 = {0,0,0,0}, acc3 = {0,0,0,0};
    for (int kc = 0; kc < 4; ++kc) {
        __syncthreads();
        const float4* src4 = reinterpret_cast<const float4*>(
            osmall + (size_t)(Bi * 384 + kc * 96) * 49);
        for (int idx = t; idx < 1176; idx += 256) {
            float4 f = src4[idx];
            int e = idx * 4;
            float vv[4] = {f.x, f.y, f.z, f.w};
#pragma unroll
            for (int j = 0; j < 4; ++j) {
                int ee = e + j;
                int kk2 = ee / 49, n2 = ee - kk2 * 49;
                Os[kk2 * 52 + n2] = vv[j];
            }
        }
        __syncthreads();
        if (t < 208) {
            const float* WtB = Wt + rgq * 4 * 388 + kc * 96 + ks;
            const float* OsB = Os + nq * 4 + ks * 52;
#pragma unroll
            for (int i = 0; i < 24; ++i) {
                float4 bb = *reinterpret_cast<const float4*>(OsB + i * 208);
                float a0 = WtB[i * 4];
                float a1 = WtB[388  + i * 4];
                float a2 = WtB[776  + i * 4];
                float a3 = WtB[1164 + i * 4];
                acc0.x += a0 * bb.x; acc0.y += a0 * bb.y; acc0.z += a0 * bb.z; acc0.w += a0 * bb.w;
                acc1.x += a1 * bb.x; acc1.y += a1 * bb.y; acc1.z += a1 * bb.z; acc1.w += a1 * bb.w;
                acc2.x += a2 * bb.x; acc2.y += a2 * bb.y; acc2.z += a2 * bb.z; acc2.w += a2 * bb.w;
                acc3.x += a3 * bb.x; acc3.y += a3 * bb.y; acc3.z += a3 * bb.z; acc3.w += a3 * bb.w;
            }
        }
    }
    __syncthreads();
    if (t < 208) {   // zbuf[ks][16 rows][52] over Os region
        int base = (ks * 16 + rgq * 4) * 52 + nq * 4;
        *reinterpret_cast<float4*>(Os + base)       = acc0;
        *reinterpret_cast<float4*>(Os + base + 52)  = acc1;
        *reinterpret_cast<float4*>(Os + base + 104) = acc2;
        *reinterpret_cast<float4*>(Os + base + 156) = acc3;
    }
    __syncthreads();
    if (t < 208) {
        int r = t / 13, nq2 = t - r * 13;
        int o0 = r * 52 + nq2 * 4;
        float4 s0 = *reinterpret_cast<const float4*>(Os + o0);
        float4 s1 = *reinterpret_cast<const float4*>(Os + o0 + 832);
        float4 s2 = *reinterpret_cast<const float4*>(Os + o0 + 1664);
        float4 s3 = *reinterpret_cast<const float4*>(Os + o0 + 2496);
        float bb = b2[ot * 16 + r];
        float4 s;
        s.x = s0.x + s1.x + s2.x + s3.x + bb;
        s.y = s0.y + s1.y + s2.y + s3.y + bb;
        s.z = s0.z + s1.z + s2.z + s3.z + bb;
        s.w = s0.w + s1.w + s2.w + s3.w + bb;
        *reinterpret_cast<float4*>(zL + o0) = s;
    }
    __syncthreads();
    // bilinear 7x7 -> 56x56 for the 16 channels, direct 2D, NT float4 stores
    size_t obase = ((size_t)(Bi * 384 + ot * 16)) * (size_t)NPIX;
    for (int qi = 0; qi < 49; ++qi) {
        int q = qi * 256 + t;                 // < 12544 = 16*784
        int ch = q / 784, rem = q - ch * 784;
        int h = rem / 14, qw = rem - h * 14;
        float sh = (h - 3.5f) * 0.125f;
        int ih0; float fh;
        if (sh <= 0.f)      { ih0 = 0; fh = 0.f; }
        else if (sh >= 6.f) { ih0 = 6; fh = 0.f; }
        else                { ih0 = (int)sh; fh = sh - (float)ih0; }
        int ih1 = min(ih0 + 1, 6);
        const float* zr = zL + ch * 52;
        vf4 o4;
#pragma unroll
        for (int j = 0; j < 4; ++j) {
            int w = qw * 4 + j;
            float sw = (w - 3.5f) * 0.125f;
            int iw0; float fw;
            if (sw <= 0.f)      { iw0 = 0; fw = 0.f; }
            else if (sw >= 6.f) { iw0 = 6; fw = 0.f; }
            else                { iw0 = (int)sw; fw = sw - (float)iw0; }
            int iw1 = min(iw0 + 1, 6);
            float a = zr[ih0 * 7 + iw0], b = zr[ih0 * 7 + iw1];
            float c = zr[ih1 * 7 + iw0], d = zr[ih1 * 7 + iw1];
            float v0 = a + fw * (b - a);
            float v1 = c + fw * (d - c);
            o4[j] = v0 + fh * (v1 - v0);
        }
        __builtin_nontemporal_store(o4,
            reinterpret_cast<vf4*>(out + obase + (size_t)q * 4));
    }
}

// ---------------------------------------------------------------------------
extern "C" void kernel_launch(void* const* d_in, const int* in_sizes, int n_in,
                              void* d_out, int out_size, void* d_ws, size_t ws_size,
                              hipStream_t stream) {
    const float* x      = (const float*)d_in[0];
    const float* proj_w = (const float*)d_in[1];
    const float* proj_b = (const float*)d_in[2];
    const float* alpha  = (const float*)d_in[3];
    const float* beta   = (const float*)d_in[4];
    const float* w2     = (const float*)d_in[5];
    const float* b2     = (const float*)d_in[6];
    float* out = (float*)d_out;
    float* ws  = (float*)d_ws;

    float* y_cat  = ws;                             // 1,720,320 f
    float* osmall = ws + (size_t)1720320;           //   301,056 f
    unsigned short* Whi = (unsigned short*)(ws + (size_t)2021376);  // 737,280 u16
    unsigned short* Wlo = (unsigned short*)(ws + (size_t)2390016);  // 737,280 u16
    unsigned short* Xhi = (unsigned short*)(ws + (size_t)2758656);  // 344,064 u16
    unsigned short* Xlo = (unsigned short*)(ws + (size_t)2930688);  // 344,064 u16
    // total ws usage ~12.4 MB

    k_prep  <<<dim3(2880),   256, 0, stream>>>(proj_w, Whi, Wlo);
    k_pool  <<<dim3(6144),   256, 0, stream>>>(x, Xhi, Xlo);
    k_gemm1m<<<dim3(14, 30), 256, 0, stream>>>(Whi, Wlo, Xhi, Xlo, proj_b, y_cat);
    k_attn  <<<dim3(128),    512, 0, stream>>>(y_cat, alpha, beta, osmall);
    k_out2  <<<dim3(384),    256, 0, stream>>>(osmall, w2, b2, out);
}

// Round 6
// 84.016 us; speedup vs baseline: 1.1888x; 1.1888x over previous
//
#include <hip/hip_runtime.h>
#include <math.h>

#define CIN    384
#define NPIX   3136      // 56*56
#define OCH    1920
#define P_PAD  896
#define ZPSTR  319488    // 16*384*52, one split-K partial plane (floats)

typedef float vf4 __attribute__((ext_vector_type(4)));
typedef __attribute__((ext_vector_type(4))) float f32x4;
typedef __attribute__((ext_vector_type(8))) short bf16x8;
typedef __attribute__((ext_vector_type(8))) unsigned short u16x8;

__device__ __forceinline__ unsigned short f2bf(float f) {
    unsigned u = __float_as_uint(f);
    u = (u + 0x7FFF + ((u >> 16) & 1)) >> 16;
    return (unsigned short)u;
}
__device__ __forceinline__ float bf2f(unsigned short h) {
    return __uint_as_float(((unsigned)h) << 16);
}

// ---------------------------------------------------------------------------
// k_front: blocks [0,6144): pool x -> Xhi/Xlo bf16 transposed [p=896][k=384]
//          blocks [6144,9024): split proj_w -> Whi/Wlo bf16
// ---------------------------------------------------------------------------
__global__ __launch_bounds__(256) void k_front(const float* __restrict__ x,
                                               const float* __restrict__ W,
                                               unsigned short* __restrict__ Xhi,
                                               unsigned short* __restrict__ Xlo,
                                               unsigned short* __restrict__ Whi,
                                               unsigned short* __restrict__ Wlo) {
    int blk = blockIdx.x;
    int t = threadIdx.x;
    if (blk >= 6144) {
        int i = (blk - 6144) * 256 + t;   // 737280 exact
        float w = W[i];
        unsigned short hi = f2bf(w);
        Whi[i] = hi;
        Wlo[i] = f2bf(w - bf2f(hi));
        return;
    }
    int Bi = blk / CIN;
    int ch = blk - Bi * CIN;
    __shared__ float ps[56][14];
    __shared__ float s14[14][14];
    const float* xp = x + (size_t)(Bi * CIN + ch) * NPIX;
    for (int p = t; p < 784; p += 256) {
        int row = p / 14, cb = p % 14;
        const vf4 v = __builtin_nontemporal_load(
            reinterpret_cast<const vf4*>(xp + row * 56 + cb * 4));
        ps[row][cb] = v.x + v.y + v.z + v.w;
    }
    __syncthreads();
    if (t < 196) {
        int ri = t / 14, cb = t % 14;
        s14[ri][cb] = ps[4*ri][cb] + ps[4*ri+1][cb] + ps[4*ri+2][cb] + ps[4*ri+3][cb];
    }
    __syncthreads();
    if (t < 49) {
        int i = t / 7, j = t % 7;
        float s = (s14[2*i][2*j] + s14[2*i][2*j+1] + s14[2*i+1][2*j] + s14[2*i+1][2*j+1])
                  * (1.0f / 64.0f);
        int p = Bi * 49 + t;
        unsigned short hi = f2bf(s);
        Xhi[(size_t)p * 384 + ch] = hi;
        Xlo[(size_t)p * 384 + ch] = f2bf(s - bf2f(hi));
    } else if (t >= 64 && t < 68) {
        int m = t - 64;
        int mi = m / 2, mj = m % 2;
        float s = 0.f;
        for (int ri = 7*mi; ri < 7*mi + 7; ++ri)
            for (int cb = 7*mj; cb < 7*mj + 7; ++cb)
                s += s14[ri][cb];
        s *= (1.0f / 784.0f);
        int p = 784 + Bi * 4 + m;
        unsigned short hi = f2bf(s);
        Xhi[(size_t)p * 384 + ch] = hi;
        Xlo[(size_t)p * 384 + ch] = f2bf(s - bf2f(hi));
    } else if (t >= 128 && t < 176 && Bi == 0) {
        int p = 848 + (t - 128);
        Xhi[(size_t)p * 384 + ch] = 0;
        Xlo[(size_t)p * 384 + ch] = 0;
    }
}

// ---------------------------------------------------------------------------
// Kernel 2: y_cat[1920][896] = W @ x + b via bf16x3 MFMA (fp32-accurate)
// ---------------------------------------------------------------------------
__global__ __launch_bounds__(256) void k_gemm1m(
        const unsigned short* __restrict__ Whi, const unsigned short* __restrict__ Wlo,
        const unsigned short* __restrict__ Xhi, const unsigned short* __restrict__ Xlo,
        const float* __restrict__ bias, float* __restrict__ y_cat) {
    int n0 = blockIdx.x * 64, m0 = blockIdx.y * 64;
    __shared__ unsigned short Ah[64][40], Al[64][40], Bh[64][40], Bl[64][40];
    int t = threadIdx.x;
    int lane = t & 63, wave = t >> 6;
    int wm = wave >> 1, wn = wave & 1;
    int fr = lane & 15, fq = lane >> 4;
    int srow = t >> 2, sck = (t & 3) * 8;
    f32x4 acc[2][2] = {};
    const size_t aoff = (size_t)(m0 + srow) * 384 + sck;
    const size_t boff = (size_t)(n0 + srow) * 384 + sck;
    for (int k0 = 0; k0 < 384; k0 += 32) {
        *(u16x8*)&Ah[srow][sck] = *(const u16x8*)(Whi + aoff + k0);
        *(u16x8*)&Al[srow][sck] = *(const u16x8*)(Wlo + aoff + k0);
        *(u16x8*)&Bh[srow][sck] = *(const u16x8*)(Xhi + boff + k0);
        *(u16x8*)&Bl[srow][sck] = *(const u16x8*)(Xlo + boff + k0);
        __syncthreads();
        bf16x8 ah[2], al[2], bh[2], bl[2];
#pragma unroll
        for (int mi = 0; mi < 2; ++mi) {
            int r = wm * 32 + mi * 16 + fr;
            ah[mi] = *(const bf16x8*)&Ah[r][fq * 8];
            al[mi] = *(const bf16x8*)&Al[r][fq * 8];
        }
#pragma unroll
        for (int ni = 0; ni < 2; ++ni) {
            int r = wn * 32 + ni * 16 + fr;
            bh[ni] = *(const bf16x8*)&Bh[r][fq * 8];
            bl[ni] = *(const bf16x8*)&Bl[r][fq * 8];
        }
#pragma unroll
        for (int mi = 0; mi < 2; ++mi)
#pragma unroll
            for (int ni = 0; ni < 2; ++ni) {
                acc[mi][ni] = __builtin_amdgcn_mfma_f32_16x16x32_bf16(ah[mi], bh[ni], acc[mi][ni], 0, 0, 0);
                acc[mi][ni] = __builtin_amdgcn_mfma_f32_16x16x32_bf16(ah[mi], bl[ni], acc[mi][ni], 0, 0, 0);
                acc[mi][ni] = __builtin_amdgcn_mfma_f32_16x16x32_bf16(al[mi], bh[ni], acc[mi][ni], 0, 0, 0);
            }
        __syncthreads();
    }
#pragma unroll
    for (int mi = 0; mi < 2; ++mi)
#pragma unroll
        for (int j = 0; j < 4; ++j) {
            int m = m0 + wm * 32 + mi * 16 + fq * 4 + j;
            float bb = bias[m];
#pragma unroll
            for (int ni = 0; ni < 2; ++ni) {
                int p = n0 + wn * 32 + ni * 16 + fr;
                y_cat[(size_t)m * P_PAD + p] = acc[mi][ni][j] + bb;
            }
        }
}

// ---------------------------------------------------------------------------
// Kernel 3: per-(B,head) cluster attention -> osmall[16][384][49]
// ---------------------------------------------------------------------------
__global__ __launch_bounds__(512) void k_attn(const float* __restrict__ y_cat,
                                              const float* __restrict__ alpha,
                                              const float* __restrict__ beta,
                                              float* __restrict__ osmall) {
    int bb = blockIdx.x;           // 128
    int Bi = bb >> 3, head = bb & 7;
    __shared__ float kL[2][48][49];
    __shared__ float vL[2][49][48];
    __shared__ float pL[48][49];
    __shared__ float kcL[2][4][48], vcL[2][4][48];
    __shared__ float e0[4][49], memb[4][49];
    __shared__ float rowmax0[4], esum0[4], msum[4];
    __shared__ float agg[8][48];
    __shared__ float anorm[8], pnorm[49];
    __shared__ float simL[8][49];
    __shared__ float assignW[8][49];
    int t = threadIdx.x;
    size_t colbase = (size_t)Bi * 49;

    for (int idx = t; idx < 5 * 2352; idx += 512) {
        int g = idx / 2352, rem = idx % 2352;
        int cc = rem / 49, n = rem % 49;
        float v = y_cat[(size_t)(g * 384 + head * 48 + cc) * P_PAD + colbase + n];
        if (g == 0)      pL[cc][n] = v;
        else if (g == 1) kL[0][cc][n] = v;
        else if (g == 2) vL[0][n][cc] = v;
        else if (g == 3) kL[1][cc][n] = v;
        else             vL[1][n][cc] = v;
    }
    for (int idx = t; idx < 768; idx += 512) {
        int i = idx / 384, rem = idx % 384;
        int kv = rem / 192, rem2 = rem % 192;
        int m = rem2 / 48, cc = rem2 % 48;
        float v = y_cat[(size_t)((1 + 2*i + kv) * 384 + head * 48 + cc) * P_PAD + 784 + Bi * 4 + m];
        if (kv == 0) kcL[i][m][cc] = v; else vcL[i][m][cc] = v;
    }
    __syncthreads();

    const float scale = 0.14433756729740643f;  // 1/sqrt(48)
    if (t < 392) {
        int i = t / 196, r = t % 196;
        int m = r / 49, n = r % 49;
        float s = 0.f;
        for (int cc = 0; cc < 48; ++cc) s += kcL[i][m][cc] * kL[i][cc][n];
        s *= scale;
        if (i == 0) e0[m][n] = s; else memb[m][n] = s;
    }
    __syncthreads();
    if (t < 4) {
        float mx = -1e30f;
        for (int n = 0; n < 49; ++n) mx = fmaxf(mx, e0[t][n]);
        rowmax0[t] = mx;
    }
    __syncthreads();
    if (t < 196) { int m = t / 49, n = t % 49; e0[m][n] = expf(e0[m][n] - rowmax0[m]); }
    __syncthreads();
    if (t < 4) { float s = 0.f; for (int n = 0; n < 49; ++n) s += e0[t][n]; esum0[t] = s; }
    if (t >= 64 && t < 113) {
        int n = t - 64;
        float a0 = memb[0][n], a1 = memb[1][n], a2 = memb[2][n], a3 = memb[3][n];
        float mx = fmaxf(fmaxf(a0, a1), fmaxf(a2, a3));
        float x0 = expf(a0 - mx), x1 = expf(a1 - mx), x2 = expf(a2 - mx), x3 = expf(a3 - mx);
        float s = x0 + x1 + x2 + x3;
        memb[0][n] = x0 / s; memb[1][n] = x1 / s; memb[2][n] = x2 / s; memb[3][n] = x3 / s;
    }
    __syncthreads();
    if (t < 4) { float s = 0.f; for (int n = 0; n < 49; ++n) s += memb[t][n]; msum[t] = s; }
    __syncthreads();
    if (t < 384) {
        int row = t / 48, cc = t % 48;
        float acc = 0.f;
        if (row < 4) {
            for (int n = 0; n < 49; ++n) acc += e0[row][n] * vL[0][n][cc];
            agg[row][cc] = acc / esum0[row] + vcL[0][row][cc];
        } else {
            int m = row - 4;
            for (int n = 0; n < 49; ++n) acc += memb[m][n] * vL[1][n][cc];
            agg[row][cc] = acc / (msum[m] + 1e-6f) + vcL[1][m][cc];
        }
    }
    __syncthreads();
    if (t < 8) {
        float s = 0.f;
        for (int cc = 0; cc < 48; ++cc) { float a = agg[t][cc]; s += a * a; }
        anorm[t] = sqrtf(s) + 1e-6f;
    }
    if (t >= 64 && t < 113) {
        int n = t - 64; float s = 0.f;
        for (int cc = 0; cc < 48; ++cc) { float a = pL[cc][n]; s += a * a; }
        pnorm[n] = sqrtf(s) + 1e-6f;
    }
    __syncthreads();
    // similarity, parallel over 8x49 (m,n)
    if (t < 392) {
        int m = t / 49, n = t - m * 49;
        float dot = 0.f;
        for (int cc = 0; cc < 48; ++cc) dot += agg[m][cc] * pL[cc][n];
        simL[m][n] = alpha[m] * (dot / (anorm[m] * pnorm[n])) + beta[m];
    }
    __syncthreads();
    if (t < 49) {
        int n = t;
        float mx = -1e30f, e[8];
        for (int m = 0; m < 8; ++m) mx = fmaxf(mx, simL[m][n]);
        float ssum = 0.f;
        for (int m = 0; m < 8; ++m) { e[m] = expf(simL[m][n] - mx); ssum += e[m]; }
        float inv = 1.f / ssum;
        for (int m = 0; m < 8; ++m) assignW[m][n] = e[m] * inv;
    }
    __syncthreads();
    for (int idx = t; idx < 2352; idx += 512) {
        int cc = idx / 49, n = idx % 49;
        float s = 0.f;
        for (int m = 0; m < 8; ++m) s += agg[m][cc] * assignW[m][n];
        osmall[((size_t)Bi * 384 + head * 48 + cc) * 49 + n] = s;
    }
}

// ---------------------------------------------------------------------------
// Kernel 4: split-K proj2 GEMM (as round 4; ~10 us known)
// ---------------------------------------------------------------------------
__global__ __launch_bounds__(256) void k_gemm2s(const float* __restrict__ osmall,
                                                const float* __restrict__ W2,
                                                float* __restrict__ zp) {
    int b = blockIdx.x;
    int kc = b & 3, ot = (b >> 2) % 24, Bi = b / 96;
    __shared__ float smem[1552 + 4992];
    int t = threadIdx.x;
    for (int idx = t; idx < 1536; idx += 256) {
        int r0 = idx / 96, c = idx - r0 * 96;
        smem[r0 * 97 + c] = W2[(size_t)(ot * 16 + r0) * 384 + kc * 96 + c];
    }
    const float4* src4 = reinterpret_cast<const float4*>(
        osmall + (size_t)(Bi * 384 + kc * 96) * 49);
    for (int idx = t; idx < 1176; idx += 256) {
        float4 f = src4[idx];
        int e = idx * 4;
        float vv[4] = {f.x, f.y, f.z, f.w};
#pragma unroll
        for (int j = 0; j < 4; ++j) {
            int ee = e + j;
            int kk2 = ee / 49, n2 = ee - kk2 * 49;
            smem[1552 + kk2 * 52 + n2] = vv[j];
        }
    }
    if (t < 96) {
        int o = 1552 + t * 52;
        smem[o + 49] = 0.f; smem[o + 50] = 0.f; smem[o + 51] = 0.f;
    }
    __syncthreads();

    float4 acc0 = {0,0,0,0}, acc1 = {0,0,0,0}, acc2 = {0,0,0,0}, acc3 = {0,0,0,0};
    int ks = 0, rgq = 0, nq = 0;
    if (t < 208) {
        ks = t / 52; int rem = t - ks * 52; rgq = rem / 13; nq = rem - rgq * 13;
        const float* WtB = smem + rgq * 4 * 97 + ks;
        const float* OsB = smem + 1552 + nq * 4 + ks * 52;
#pragma unroll
        for (int i = 0; i < 24; ++i) {
            float4 bb = *reinterpret_cast<const float4*>(OsB + i * 208);
            float a0 = WtB[i * 4];
            float a1 = WtB[97  + i * 4];
            float a2 = WtB[194 + i * 4];
            float a3 = WtB[291 + i * 4];
            acc0.x += a0 * bb.x; acc0.y += a0 * bb.y; acc0.z += a0 * bb.z; acc0.w += a0 * bb.w;
            acc1.x += a1 * bb.x; acc1.y += a1 * bb.y; acc1.z += a1 * bb.z; acc1.w += a1 * bb.w;
            acc2.x += a2 * bb.x; acc2.y += a2 * bb.y; acc2.z += a2 * bb.z; acc2.w += a2 * bb.w;
            acc3.x += a3 * bb.x; acc3.y += a3 * bb.y; acc3.z += a3 * bb.z; acc3.w += a3 * bb.w;
        }
    }
    __syncthreads();
    if (t < 208) {
        int base = ((ks * 16 + rgq * 4) * 13 + nq) * 4;
        *reinterpret_cast<float4*>(smem + 1552 + base)       = acc0;
        *reinterpret_cast<float4*>(smem + 1552 + base + 52)  = acc1;
        *reinterpret_cast<float4*>(smem + 1552 + base + 104) = acc2;
        *reinterpret_cast<float4*>(smem + 1552 + base + 156) = acc3;
    }
    __syncthreads();
    if (t < 208) {
        int r = t / 13, nq2 = t - r * 13;
        int o0 = (r * 13 + nq2) * 4;
        float4 s0 = *reinterpret_cast<const float4*>(smem + 1552 + o0);
        float4 s1 = *reinterpret_cast<const float4*>(smem + 1552 + o0 + 832);
        float4 s2 = *reinterpret_cast<const float4*>(smem + 1552 + o0 + 1664);
        float4 s3 = *reinterpret_cast<const float4*>(smem + 1552 + o0 + 2496);
        float4 s;
        s.x = s0.x + s1.x + s2.x + s3.x;
        s.y = s0.y + s1.y + s2.y + s3.y;
        s.z = s0.z + s1.z + s2.z + s3.z;
        s.w = s0.w + s1.w + s2.w + s3.w;
        *reinterpret_cast<float4*>(zp + (size_t)kc * ZPSTR +
            ((size_t)(Bi * 384 + ot * 16 + r)) * 52 + nq2 * 4) = s;
    }
}

// ---------------------------------------------------------------------------
// Kernel 5: sum 4 split-K partials + bias, bilinear 7x7 -> 56x56
// 4 channels per block: 1536 blocks, 8 KB LDS, 50 KB contiguous NT writes
// ---------------------------------------------------------------------------
__global__ __launch_bounds__(256) void k_up4(const float* __restrict__ zp,
                                             const float* __restrict__ b2,
                                             float* __restrict__ out) {
    int blk = blockIdx.x;          // 1536 = 16 * 96
    int Bi = blk / 96, cg = blk - Bi * 96;
    int ch0 = cg * 4;
    __shared__ float zL[4][52];
    __shared__ float tmp[4][56][8];
    int t = threadIdx.x;
    if (t < 196) {
        int c = t / 49, n = t - c * 49;
        size_t base = (size_t)(Bi * 384 + ch0 + c) * 52 + n;
        zL[c][n] = zp[base] + zp[base + ZPSTR] + zp[base + 2 * (size_t)ZPSTR]
                 + zp[base + 3 * (size_t)ZPSTR] + b2[ch0 + c];
    }
    __syncthreads();
    for (int idx = t; idx < 1568; idx += 256) {   // 4ch x 56h x 7iw
        int c = idx / 392, rem = idx - c * 392;
        int h = rem / 7, iw = rem - h * 7;
        float sh = (h - 3.5f) * 0.125f;
        int ih0; float fh;
        if (sh <= 0.f)      { ih0 = 0; fh = 0.f; }
        else if (sh >= 6.f) { ih0 = 6; fh = 0.f; }
        else                { ih0 = (int)sh; fh = sh - (float)ih0; }
        int ih1 = min(ih0 + 1, 6);
        float z0 = zL[c][ih0 * 7 + iw];
        tmp[c][h][iw] = z0 + fh * (zL[c][ih1 * 7 + iw] - z0);
    }
    __syncthreads();
    size_t obase = ((size_t)(Bi * 384 + ch0)) * (size_t)NPIX;
    for (int q = t; q < 3136; q += 256) {         // 4 planes x 784 quads
        int c = q / 784, rem = q - c * 784;
        int h = rem / 14, qw = rem - h * 14;
        const float* tr = &tmp[c][h][0];
        vf4 o4;
#pragma unroll
        for (int j = 0; j < 4; ++j) {
            int w = qw * 4 + j;
            float sw = (w - 3.5f) * 0.125f;
            int iw0; float fw;
            if (sw <= 0.f)      { iw0 = 0; fw = 0.f; }
            else if (sw >= 6.f) { iw0 = 6; fw = 0.f; }
            else                { iw0 = (int)sw; fw = sw - (float)iw0; }
            int iw1 = min(iw0 + 1, 6);
            float t0 = tr[iw0];
            o4[j] = t0 + fw * (tr[iw1] - t0);
        }
        __builtin_nontemporal_store(o4,
            reinterpret_cast<vf4*>(out + obase + (size_t)q * 4));
    }
}

// ---------------------------------------------------------------------------
extern "C" void kernel_launch(void* const* d_in, const int* in_sizes, int n_in,
                              void* d_out, int out_size, void* d_ws, size_t ws_size,
                              hipStream_t stream) {
    const float* x      = (const float*)d_in[0];
    const float* proj_w = (const float*)d_in[1];
    const float* proj_b = (const float*)d_in[2];
    const float* alpha  = (const float*)d_in[3];
    const float* beta   = (const float*)d_in[4];
    const float* w2     = (const float*)d_in[5];
    const float* b2     = (const float*)d_in[6];
    float* out = (float*)d_out;
    float* ws  = (float*)d_ws;

    float* y_cat  = ws;                           // 1,720,320 f
    float* osmall = ws + (size_t)1720320;         //   301,056 f
    // region C: bf16 staging (dead after gemm1m), reused for zp
    unsigned short* Whi = (unsigned short*)(ws + (size_t)2021376);  // 737,280 u16
    unsigned short* Wlo = (unsigned short*)(ws + (size_t)2389  * 1000 + 16 * 1); // placeholder (overwritten below)
    Wlo = (unsigned short*)(ws + (size_t)2390016);                  // 737,280 u16
    unsigned short* Xhi = (unsigned short*)(ws + (size_t)2758656);  // 344,064 u16
    unsigned short* Xlo = (unsigned short*)(ws + (size_t)2930688);  // 344,064 u16
    float* zp = ws + (size_t)2021376;             // 1,277,952 f (overlaps bf16 region)
    // total ws: 3,299,328 floats ~= 13.2 MB

    k_front <<<dim3(9024),   256, 0, stream>>>(x, proj_w, Xhi, Xlo, Whi, Wlo);
    k_gemm1m<<<dim3(14, 30), 256, 0, stream>>>(Whi, Wlo, Xhi, Xlo, proj_b, y_cat);
    k_attn  <<<dim3(128),    512, 0, stream>>>(y_cat, alpha, beta, osmall);
    k_gemm2s<<<dim3(1536),   256, 0, stream>>>(osmall, w2, zp);
    k_up4   <<<dim3(1536),   256, 0, stream>>>(zp, b2, out);
}

// Round 7
// 78.826 us; speedup vs baseline: 1.2671x; 1.0658x over previous
//
#include <hip/hip_runtime.h>
#include <math.h>

#define CIN    384
#define NPIX   3136      // 56*56
#define P_PAD  896
#define ZPSTR  319488    // 16*384*52, one split-K partial plane (floats)

typedef float vf4 __attribute__((ext_vector_type(4)));
typedef __attribute__((ext_vector_type(4))) float f32x4;
typedef __attribute__((ext_vector_type(8))) short bf16x8;
typedef __attribute__((ext_vector_type(8))) unsigned short u16x8;

__device__ __forceinline__ unsigned short f2bf(float f) {
    unsigned u = __float_as_uint(f);
    u = (u + 0x7FFF + ((u >> 16) & 1)) >> 16;
    return (unsigned short)u;
}
__device__ __forceinline__ float bf2f(unsigned short h) {
    return __uint_as_float(((unsigned)h) << 16);
}

// ---------------------------------------------------------------------------
// k_front: blocks [0,6144): pool x -> Xhi/Xlo bf16 transposed [p=896][k=384]
//          blocks [6144,9024): split proj_w -> Whi/Wlo bf16
// ---------------------------------------------------------------------------
__global__ __launch_bounds__(256) void k_front(const float* __restrict__ x,
                                               const float* __restrict__ W,
                                               unsigned short* __restrict__ Xhi,
                                               unsigned short* __restrict__ Xlo,
                                               unsigned short* __restrict__ Whi,
                                               unsigned short* __restrict__ Wlo) {
    int blk = blockIdx.x;
    int t = threadIdx.x;
    if (blk >= 6144) {
        int i = (blk - 6144) * 256 + t;   // 737280 exact
        float w = W[i];
        unsigned short hi = f2bf(w);
        Whi[i] = hi;
        Wlo[i] = f2bf(w - bf2f(hi));
        return;
    }
    int Bi = blk / CIN;
    int ch = blk - Bi * CIN;
    __shared__ float ps[56][14];
    __shared__ float s14[14][14];
    const float* xp = x + (size_t)(Bi * CIN + ch) * NPIX;
    for (int p = t; p < 784; p += 256) {
        int row = p / 14, cb = p % 14;
        const vf4 v = __builtin_nontemporal_load(
            reinterpret_cast<const vf4*>(xp + row * 56 + cb * 4));
        ps[row][cb] = v.x + v.y + v.z + v.w;
    }
    __syncthreads();
    if (t < 196) {
        int ri = t / 14, cb = t % 14;
        s14[ri][cb] = ps[4*ri][cb] + ps[4*ri+1][cb] + ps[4*ri+2][cb] + ps[4*ri+3][cb];
    }
    __syncthreads();
    if (t < 49) {
        int i = t / 7, j = t % 7;
        float s = (s14[2*i][2*j] + s14[2*i][2*j+1] + s14[2*i+1][2*j] + s14[2*i+1][2*j+1])
                  * (1.0f / 64.0f);
        int p = Bi * 49 + t;
        unsigned short hi = f2bf(s);
        Xhi[(size_t)p * 384 + ch] = hi;
        Xlo[(size_t)p * 384 + ch] = f2bf(s - bf2f(hi));
    } else if (t >= 64 && t < 68) {
        int m = t - 64;
        int mi = m / 2, mj = m % 2;
        float s = 0.f;
        for (int ri = 7*mi; ri < 7*mi + 7; ++ri)
            for (int cb = 7*mj; cb < 7*mj + 7; ++cb)
                s += s14[ri][cb];
        s *= (1.0f / 784.0f);
        int p = 784 + Bi * 4 + m;
        unsigned short hi = f2bf(s);
        Xhi[(size_t)p * 384 + ch] = hi;
        Xlo[(size_t)p * 384 + ch] = f2bf(s - bf2f(hi));
    }
}

// ---------------------------------------------------------------------------
// k_fuse: per-(Bi,head) block: y = W@x+b (240x53, bf16x3 MFMA, y in LDS)
//         then cluster attention -> osmall[16][384][49]. 128 blocks, 512 thr.
// ---------------------------------------------------------------------------
__global__ __launch_bounds__(512) void k_fuse(
        const unsigned short* __restrict__ Whi, const unsigned short* __restrict__ Wlo,
        const unsigned short* __restrict__ Xhi, const unsigned short* __restrict__ Xlo,
        const float* __restrict__ proj_b,
        const float* __restrict__ alpha, const float* __restrict__ beta,
        float* __restrict__ osmall) {
    int bb = blockIdx.x;           // 128
    int Bi = bb >> 3, head = bb & 7;
    // yT[240][69] fp32 (66.2 KB); staging aliased into the same memory
    __shared__ float yT[16560];
    __shared__ float e0[4][49], memb[4][49];
    __shared__ float rowmax0[4], esum0[4], msum[4];
    __shared__ float agg[8][48];
    __shared__ float anorm[8], pnorm[49];
    __shared__ float simL[8][49];
    __shared__ float assignW[8][49];
    unsigned short* sAh = (unsigned short*)yT;   // 240*40
    unsigned short* sAl = sAh + 9600;            // 240*40
    unsigned short* sBh = sAl + 9600;            // 64*40
    unsigned short* sBl = sBh + 2560;            // 64*40 (ends 24320 shorts)
    int t = threadIdx.x;
    int lane = t & 63, w = t >> 6;
    int fr = lane & 15, fq = lane >> 4;

    // ---- GEMM: 240x64 tile, K=384 in 12 steps ----
    f32x4 acc[2][4] = {};
    for (int k0 = 0; k0 < 384; k0 += 32) {
        for (int c = t; c < 960; c += 512) {       // A: 240 rows x 4 chunks
            int row = c >> 2, ko = (c & 3) * 8;
            int g = row / 48, cc = row - g * 48;
            size_t goff = (size_t)(g * 384 + head * 48 + cc) * 384 + k0 + ko;
            *(u16x8*)&sAh[row * 40 + ko] = *(const u16x8*)(Whi + goff);
            *(u16x8*)&sAl[row * 40 + ko] = *(const u16x8*)(Wlo + goff);
        }
        if (t < 212) {                             // B: 53 rows x 4 chunks
            int row = t >> 2, ko = (t & 3) * 8;
            int p = row < 49 ? Bi * 49 + row : 784 + Bi * 4 + (row - 49);
            size_t goff = (size_t)p * 384 + k0 + ko;
            *(u16x8*)&sBh[row * 40 + ko] = *(const u16x8*)(Xhi + goff);
            *(u16x8*)&sBl[row * 40 + ko] = *(const u16x8*)(Xlo + goff);
        }
        __syncthreads();
        bf16x8 bh[4], bl[4];
#pragma unroll
        for (int nt = 0; nt < 4; ++nt) {
            int r = nt * 16 + fr;
            bh[nt] = *(const bf16x8*)&sBh[r * 40 + fq * 8];
            bl[nt] = *(const bf16x8*)&sBl[r * 40 + fq * 8];
        }
#pragma unroll
        for (int mi = 0; mi < 2; ++mi) {
            int mt = 2 * w + mi;
            if (mt < 15) {
                int r = mt * 16 + fr;
                bf16x8 ah = *(const bf16x8*)&sAh[r * 40 + fq * 8];
                bf16x8 al = *(const bf16x8*)&sAl[r * 40 + fq * 8];
#pragma unroll
                for (int nt = 0; nt < 4; ++nt) {
                    acc[mi][nt] = __builtin_amdgcn_mfma_f32_16x16x32_bf16(ah, bh[nt], acc[mi][nt], 0, 0, 0);
                    acc[mi][nt] = __builtin_amdgcn_mfma_f32_16x16x32_bf16(ah, bl[nt], acc[mi][nt], 0, 0, 0);
                    acc[mi][nt] = __builtin_amdgcn_mfma_f32_16x16x32_bf16(al, bh[nt], acc[mi][nt], 0, 0, 0);
                }
            }
        }
        __syncthreads();
    }
    // write y tile to LDS (staging dead). C/D: col=lane&15, row=(lane>>4)*4+j
#pragma unroll
    for (int mi = 0; mi < 2; ++mi) {
        int mt = 2 * w + mi;
        if (mt < 15) {
#pragma unroll
            for (int j = 0; j < 4; ++j) {
                int m = mt * 16 + fq * 4 + j;
                int g = m / 48, cc = m - g * 48;
                float bb = proj_b[g * 384 + head * 48 + cc];
#pragma unroll
                for (int nt = 0; nt < 4; ++nt)
                    yT[m * 69 + nt * 16 + fr] = acc[mi][nt][j] + bb;
            }
        }
    }
    __syncthreads();

    // ---- attention on yT ----
    // rows: p = 0..47 | k0 = 48.. | v0 = 96.. | k1 = 144.. | v1 = 192..
    // cols: n<49 agents; 49+m clusters
    const float scale = 0.14433756729740643f;  // 1/sqrt(48)
    if (t < 392) {
        int i = t / 196, r = t % 196;
        int m = r / 49, n = r % 49;
        int rbase = 48 + 96 * i;
        float s = 0.f;
        for (int cc = 0; cc < 48; ++cc)
            s += yT[(rbase + cc) * 69 + 49 + m] * yT[(rbase + cc) * 69 + n];
        s *= scale;
        if (i == 0) e0[m][n] = s; else memb[m][n] = s;
    }
    __syncthreads();
    if (t < 4) {
        float mx = -1e30f;
        for (int n = 0; n < 49; ++n) mx = fmaxf(mx, e0[t][n]);
        rowmax0[t] = mx;
    }
    __syncthreads();
    if (t < 196) { int m = t / 49, n = t % 49; e0[m][n] = expf(e0[m][n] - rowmax0[m]); }
    __syncthreads();
    if (t < 4) { float s = 0.f; for (int n = 0; n < 49; ++n) s += e0[t][n]; esum0[t] = s; }
    if (t >= 64 && t < 113) {
        int n = t - 64;
        float a0 = memb[0][n], a1 = memb[1][n], a2 = memb[2][n], a3 = memb[3][n];
        float mx = fmaxf(fmaxf(a0, a1), fmaxf(a2, a3));
        float x0 = expf(a0 - mx), x1 = expf(a1 - mx), x2 = expf(a2 - mx), x3 = expf(a3 - mx);
        float s = x0 + x1 + x2 + x3;
        memb[0][n] = x0 / s; memb[1][n] = x1 / s; memb[2][n] = x2 / s; memb[3][n] = x3 / s;
    }
    __syncthreads();
    if (t < 4) { float s = 0.f; for (int n = 0; n < 49; ++n) s += memb[t][n]; msum[t] = s; }
    __syncthreads();
    if (t < 384) {
        int row = t / 48, cc = t % 48;
        float a = 0.f;
        if (row < 4) {
            const float* vr = &yT[(96 + cc) * 69];
            for (int n = 0; n < 49; ++n) a += e0[row][n] * vr[n];
            agg[row][cc] = a / esum0[row] + vr[49 + row];
        } else {
            int m = row - 4;
            const float* vr = &yT[(192 + cc) * 69];
            for (int n = 0; n < 49; ++n) a += memb[m][n] * vr[n];
            agg[row][cc] = a / (msum[m] + 1e-6f) + vr[49 + m];
        }
    }
    __syncthreads();
    if (t < 8) {
        float s = 0.f;
        for (int cc = 0; cc < 48; ++cc) { float a = agg[t][cc]; s += a * a; }
        anorm[t] = sqrtf(s) + 1e-6f;
    }
    if (t >= 64 && t < 113) {
        int n = t - 64; float s = 0.f;
        for (int cc = 0; cc < 48; ++cc) { float a = yT[cc * 69 + n]; s += a * a; }
        pnorm[n] = sqrtf(s) + 1e-6f;
    }
    __syncthreads();
    if (t < 392) {
        int m = t / 49, n = t - m * 49;
        float dot = 0.f;
        for (int cc = 0; cc < 48; ++cc) dot += agg[m][cc] * yT[cc * 69 + n];
        simL[m][n] = alpha[m] * (dot / (anorm[m] * pnorm[n])) + beta[m];
    }
    __syncthreads();
    if (t < 49) {
        int n = t;
        float mx = -1e30f, e[8];
        for (int m = 0; m < 8; ++m) mx = fmaxf(mx, simL[m][n]);
        float ssum = 0.f;
        for (int m = 0; m < 8; ++m) { e[m] = expf(simL[m][n] - mx); ssum += e[m]; }
        float inv = 1.f / ssum;
        for (int m = 0; m < 8; ++m) assignW[m][n] = e[m] * inv;
    }
    __syncthreads();
    for (int idx = t; idx < 2352; idx += 512) {
        int cc = idx / 49, n = idx % 49;
        float s = 0.f;
        for (int m = 0; m < 8; ++m) s += agg[m][cc] * assignW[m][n];
        osmall[((size_t)Bi * 384 + head * 48 + cc) * 49 + n] = s;
    }
}

// ---------------------------------------------------------------------------
// Kernel 3: split-K proj2 GEMM -> zp partials
// ---------------------------------------------------------------------------
__global__ __launch_bounds__(256) void k_gemm2s(const float* __restrict__ osmall,
                                                const float* __restrict__ W2,
                                                float* __restrict__ zp) {
    int b = blockIdx.x;
    int kc = b & 3, ot = (b >> 2) % 24, Bi = b / 96;
    __shared__ float smem[1552 + 4992];
    int t = threadIdx.x;
    for (int idx = t; idx < 1536; idx += 256) {
        int r0 = idx / 96, c = idx - r0 * 96;
        smem[r0 * 97 + c] = W2[(size_t)(ot * 16 + r0) * 384 + kc * 96 + c];
    }
    const float4* src4 = reinterpret_cast<const float4*>(
        osmall + (size_t)(Bi * 384 + kc * 96) * 49);
    for (int idx = t; idx < 1176; idx += 256) {
        float4 f = src4[idx];
        int e = idx * 4;
        float vv[4] = {f.x, f.y, f.z, f.w};
#pragma unroll
        for (int j = 0; j < 4; ++j) {
            int ee = e + j;
            int kk2 = ee / 49, n2 = ee - kk2 * 49;
            smem[1552 + kk2 * 52 + n2] = vv[j];
        }
    }
    if (t < 96) {
        int o = 1552 + t * 52;
        smem[o + 49] = 0.f; smem[o + 50] = 0.f; smem[o + 51] = 0.f;
    }
    __syncthreads();

    float4 acc0 = {0,0,0,0}, acc1 = {0,0,0,0}, acc2 = {0,0,0,0}, acc3 = {0,0,0,0};
    int ks = 0, rgq = 0, nq = 0;
    if (t < 208) {
        ks = t / 52; int rem = t - ks * 52; rgq = rem / 13; nq = rem - rgq * 13;
        const float* WtB = smem + rgq * 4 * 97 + ks;
        const float* OsB = smem + 1552 + nq * 4 + ks * 52;
#pragma unroll
        for (int i = 0; i < 24; ++i) {
            float4 bb = *reinterpret_cast<const float4*>(OsB + i * 208);
            float a0 = WtB[i * 4];
            float a1 = WtB[97  + i * 4];
            float a2 = WtB[194 + i * 4];
            float a3 = WtB[291 + i * 4];
            acc0.x += a0 * bb.x; acc0.y += a0 * bb.y; acc0.z += a0 * bb.z; acc0.w += a0 * bb.w;
            acc1.x += a1 * bb.x; acc1.y += a1 * bb.y; acc1.z += a1 * bb.z; acc1.w += a1 * bb.w;
            acc2.x += a2 * bb.x; acc2.y += a2 * bb.y; acc2.z += a2 * bb.z; acc2.w += a2 * bb.w;
            acc3.x += a3 * bb.x; acc3.y += a3 * bb.y; acc3.z += a3 * bb.z; acc3.w += a3 * bb.w;
        }
    }
    __syncthreads();
    if (t < 208) {
        int base = ((ks * 16 + rgq * 4) * 13 + nq) * 4;
        *reinterpret_cast<float4*>(smem + 1552 + base)       = acc0;
        *reinterpret_cast<float4*>(smem + 1552 + base + 52)  = acc1;
        *reinterpret_cast<float4*>(smem + 1552 + base + 104) = acc2;
        *reinterpret_cast<float4*>(smem + 1552 + base + 156) = acc3;
    }
    __syncthreads();
    if (t < 208) {
        int r = t / 13, nq2 = t - r * 13;
        int o0 = (r * 13 + nq2) * 4;
        float4 s0 = *reinterpret_cast<const float4*>(smem + 1552 + o0);
        float4 s1 = *reinterpret_cast<const float4*>(smem + 1552 + o0 + 832);
        float4 s2 = *reinterpret_cast<const float4*>(smem + 1552 + o0 + 1664);
        float4 s3 = *reinterpret_cast<const float4*>(smem + 1552 + o0 + 2496);
        float4 s;
        s.x = s0.x + s1.x + s2.x + s3.x;
        s.y = s0.y + s1.y + s2.y + s3.y;
        s.z = s0.z + s1.z + s2.z + s3.z;
        s.w = s0.w + s1.w + s2.w + s3.w;
        *reinterpret_cast<float4*>(zp + (size_t)kc * ZPSTR +
            ((size_t)(Bi * 384 + ot * 16 + r)) * 52 + nq2 * 4) = s;
    }
}

// ---------------------------------------------------------------------------
// Kernel 4: sum split-K partials + bias, bilinear 7x7 -> 56x56 (4 ch/block)
// ---------------------------------------------------------------------------
__global__ __launch_bounds__(256) void k_up4(const float* __restrict__ zp,
                                             const float* __restrict__ b2,
                                             float* __restrict__ out) {
    int blk = blockIdx.x;          // 1536 = 16 * 96
    int Bi = blk / 96, cg = blk - Bi * 96;
    int ch0 = cg * 4;
    __shared__ float zL[4][52];
    __shared__ float tmp[4][56][8];
    int t = threadIdx.x;
    if (t < 196) {
        int c = t / 49, n = t - c * 49;
        size_t base = (size_t)(Bi * 384 + ch0 + c) * 52 + n;
        zL[c][n] = zp[base] + zp[base + ZPSTR] + zp[base + 2 * (size_t)ZPSTR]
                 + zp[base + 3 * (size_t)ZPSTR] + b2[ch0 + c];
    }
    __syncthreads();
    for (int idx = t; idx < 1568; idx += 256) {   // 4ch x 56h x 7iw
        int c = idx / 392, rem = idx - c * 392;
        int h = rem / 7, iw = rem - h * 7;
        float sh = (h - 3.5f) * 0.125f;
        int ih0; float fh;
        if (sh <= 0.f)      { ih0 = 0; fh = 0.f; }
        else if (sh >= 6.f) { ih0 = 6; fh = 0.f; }
        else                { ih0 = (int)sh; fh = sh - (float)ih0; }
        int ih1 = min(ih0 + 1, 6);
        float z0 = zL[c][ih0 * 7 + iw];
        tmp[c][h][iw] = z0 + fh * (zL[c][ih1 * 7 + iw] - z0);
    }
    __syncthreads();
    size_t obase = ((size_t)(Bi * 384 + ch0)) * (size_t)NPIX;
    for (int q = t; q < 3136; q += 256) {         // 4 planes x 784 quads
        int c = q / 784, rem = q - c * 784;
        int h = rem / 14, qw = rem - h * 14;
        const float* tr = &tmp[c][h][0];
        vf4 o4;
#pragma unroll
        for (int j = 0; j < 4; ++j) {
            int w = qw * 4 + j;
            float sw = (w - 3.5f) * 0.125f;
            int iw0; float fw;
            if (sw <= 0.f)      { iw0 = 0; fw = 0.f; }
            else if (sw >= 6.f) { iw0 = 6; fw = 0.f; }
            else                { iw0 = (int)sw; fw = sw - (float)iw0; }
            int iw1 = min(iw0 + 1, 6);
            float t0 = tr[iw0];
            o4[j] = t0 + fw * (tr[iw1] - t0);
        }
        __builtin_nontemporal_store(o4,
            reinterpret_cast<vf4*>(out + obase + (size_t)q * 4));
    }
}

// ---------------------------------------------------------------------------
extern "C" void kernel_launch(void* const* d_in, const int* in_sizes, int n_in,
                              void* d_out, int out_size, void* d_ws, size_t ws_size,
                              hipStream_t stream) {
    const float* x      = (const float*)d_in[0];
    const float* proj_w = (const float*)d_in[1];
    const float* proj_b = (const float*)d_in[2];
    const float* alpha  = (const float*)d_in[3];
    const float* beta   = (const float*)d_in[4];
    const float* w2     = (const float*)d_in[5];
    const float* b2     = (const float*)d_in[6];
    float* out = (float*)d_out;
    float* ws  = (float*)d_ws;

    float* osmall = ws;                                            //   301,056 f
    unsigned short* Whi = (unsigned short*)(ws + (size_t)301056);  //   737,280 u16
    unsigned short* Wlo = (unsigned short*)(ws + (size_t)669696);  //   737,280 u16
    unsigned short* Xhi = (unsigned short*)(ws + (size_t)1038336); //   344,064 u16
    unsigned short* Xlo = (unsigned short*)(ws + (size_t)1210368); //   344,064 u16
    float* zp = ws + (size_t)1382400;                              // 1,277,952 f
    // total ws: 2,660,352 floats ~= 10.6 MB

    k_front <<<dim3(9024), 256, 0, stream>>>(x, proj_w, Xhi, Xlo, Whi, Wlo);
    k_fuse  <<<dim3(128),  512, 0, stream>>>(Whi, Wlo, Xhi, Xlo, proj_b, alpha, beta, osmall);
    k_gemm2s<<<dim3(1536), 256, 0, stream>>>(osmall, w2, zp);
    k_up4   <<<dim3(1536), 256, 0, stream>>>(zp, b2, out);
}